// Round 2
// baseline (1383.997 us; speedup 1.0000x reference)
//
#include <hip/hip_runtime.h>
#include <stdint.h>

#define M_NODES 100000
#define NUM_EDGES 3200000
#define IN_DIM 512
#define HIDDEN 256
#define NCLS 64

typedef __bf16 bf16x8 __attribute__((ext_vector_type(8)));
typedef float floatx4 __attribute__((ext_vector_type(4)));
typedef unsigned int uintx4 __attribute__((ext_vector_type(4)));
typedef unsigned short ushortx8 __attribute__((ext_vector_type(8)));

// ---- workspace layout (bytes) ----
// rp    : int[100001]            @ 0
// w1t   : ushort[256*512]        @ 400016
// w2t   : ushort[64*256]         @ 662160
// h1    : ushort[100000*256]     @ 694928    (dead after gemm2)
// bB    : ushort[100000*64]      @ 694928    (alias: first 12.8MB of h1)
// ecol2 : int[3200000]           @ 13494928  (alias: h1 tail, written after gemm2)
// eval2 : float[3200000]         @ 26294928  (alias: h1 tail)
// fA    : float[100000*64]       @ 51894928
// fB    : float[100000*64]       @ 77494928
// bA    : ushort[100000*64]      @ 103094928
#define WS_ROWPTR 0
#define WS_W1T    400016
#define WS_W2T    662160
#define WS_H1     694928
#define WS_BB     694928
#define WS_ECOL2  13494928
#define WS_EVAL2  26294928
#define WS_FA     51894928
#define WS_FB     77494928
#define WS_BA     103094928

// ---------------- weight transpose + bf16 convert ----------------
__global__ __launch_bounds__(256) void prep_weights(
    const float* __restrict__ W1, const float* __restrict__ W2,
    unsigned short* __restrict__ w1t, unsigned short* __restrict__ w2t) {
  int tid = blockIdx.x * 256 + threadIdx.x;
  if (tid < IN_DIM * HIDDEN) {
    int n = tid >> 9;
    int k = tid & 511;
    __bf16 v = (__bf16)W1[k * HIDDEN + n];
    w1t[tid] = __builtin_bit_cast(unsigned short, v);
  } else {
    int idx = tid - IN_DIM * HIDDEN;
    if (idx < HIDDEN * NCLS) {
      int n = idx >> 8;
      int k = idx & 255;
      __bf16 v = (__bf16)W2[k * NCLS + n];
      w2t[idx] = __builtin_bit_cast(unsigned short, v);
    }
  }
}

// ---------------- row_ptr via binary search over sorted edge_row ----------------
__global__ __launch_bounds__(256) void build_rowptr(
    const int* __restrict__ erow, int* __restrict__ rp) {
  int r = blockIdx.x * 256 + threadIdx.x;
  if (r > M_NODES) return;
  if (r == M_NODES) { rp[r] = NUM_EDGES; return; }
  int lo = 0, hi = NUM_EDGES;
  while (lo < hi) {
    int mid = (lo + hi) >> 1;
    if (erow[mid] < r) lo = mid + 1; else hi = mid;
  }
  rp[r] = lo;
}

// ---------------- bucket edges within each row by col>>14 ----------------
// Purpose: all concurrent spmm blocks walk their rows in the same col-bucket
// order, so the gather working set at any instant is a ~2MB window of tb that
// fits per-XCD L2 (vs 12.8MB table -> ~70% L2 miss unbucketed).
// Counters: 7 buckets (col>>14 in 0..6), packed 8-bit fields in one u64 so
// runtime bucket indexing stays in registers (no scratch). deg<=~70 << 255.
__global__ __launch_bounds__(256) void bucket_edges(
    const int* __restrict__ rp, const int* __restrict__ cols,
    const float* __restrict__ vals, int* __restrict__ cols2,
    float* __restrict__ vals2) {
  int r = blockIdx.x * 256 + threadIdx.x;
  if (r >= M_NODES) return;
  const int s = rp[r], e = rp[r + 1];
  unsigned long long cnt = 0;
  for (int i = s; i < e; ++i) {
    const int b = cols[i] >> 14;
    cnt += 1ull << (b * 8);
  }
  // exclusive prefix over packed byte fields: pre[b] = sum_{j<b} cnt[j]
  unsigned long long pre = (cnt << 8) + (cnt << 16) + (cnt << 24) + (cnt << 32)
                         + (cnt << 40) + (cnt << 48) + (cnt << 56);
  for (int i = s; i < e; ++i) {
    const int c = cols[i];
    const float v = vals[i];
    const int b = c >> 14;
    const int off = (int)((pre >> (b * 8)) & 0xffull);
    pre += 1ull << (b * 8);
    cols2[s + off] = c;
    vals2[s + off] = v;
  }
}

// ---------------- GEMM1: h1 = relu(x @ W1 + b1), bf16 out ----------------
// Block = 32 rows; 4 waves split N into 64-col slices. x-tile staging is
// double-buffered through registers: next K-tile's global loads issue before
// the current tile's MFMA phase, hiding the L3 latency that previously sat
// exposed between the two barriers (MfmaUtil was 6%).
__global__ __launch_bounds__(256) void gemm1(
    const float* __restrict__ x, const unsigned short* __restrict__ w1t,
    const float* __restrict__ b1, unsigned short* __restrict__ h1) {
  __shared__ float xs[32 * 68];
  const int wave = threadIdx.x >> 6, lane = threadIdx.x & 63;
  const int m0 = blockIdx.x * 32;
  const int n0 = wave * 64;
  const int l15 = lane & 15, quad = lane >> 4;
  const int t = threadIdx.x;
  const int srow = t >> 3;          // 0..31: staged row
  const int skq = (t & 7) * 8;      // float offset within row (8 floats/thread)

  floatx4 ra, rb;
  {
    const float* src = x + (size_t)(m0 + srow) * IN_DIM + skq;
    ra = *(const floatx4*)src;
    rb = *(const floatx4*)(src + 4);
  }

  floatx4 acc[2][4] = {};
  for (int kb = 0; kb < IN_DIM; kb += 64) {
    __syncthreads();
    *(floatx4*)(xs + srow * 68 + skq) = ra;
    *(floatx4*)(xs + srow * 68 + skq + 4) = rb;
    __syncthreads();
    if (kb + 64 < IN_DIM) {
      const float* src = x + (size_t)(m0 + srow) * IN_DIM + kb + 64 + skq;
      ra = *(const floatx4*)src;
      rb = *(const floatx4*)(src + 4);
    }

    bf16x8 afrag[2][2];
    bf16x8 bfrag[2][4];
#pragma unroll
    for (int ks = 0; ks < 2; ks++) {
#pragma unroll
      for (int tm = 0; tm < 2; tm++) {
        const float* p = xs + (tm * 16 + l15) * 68 + ks * 32 + quad * 8;
        floatx4 a0 = *(const floatx4*)p;
        floatx4 a1 = *(const floatx4*)(p + 4);
        bf16x8 f;
        f[0] = (__bf16)a0[0]; f[1] = (__bf16)a0[1]; f[2] = (__bf16)a0[2]; f[3] = (__bf16)a0[3];
        f[4] = (__bf16)a1[0]; f[5] = (__bf16)a1[1]; f[6] = (__bf16)a1[2]; f[7] = (__bf16)a1[3];
        afrag[ks][tm] = f;
      }
      const int k = kb + ks * 32 + quad * 8;
#pragma unroll
      for (int tn = 0; tn < 4; tn++)
        bfrag[ks][tn] = *(const bf16x8*)(w1t + (size_t)(n0 + tn * 16 + l15) * IN_DIM + k);
    }
#pragma unroll
    for (int ks = 0; ks < 2; ks++)
#pragma unroll
      for (int tm = 0; tm < 2; tm++)
#pragma unroll
        for (int tn = 0; tn < 4; tn++)
          acc[tm][tn] = __builtin_amdgcn_mfma_f32_16x16x32_bf16(afrag[ks][tm], bfrag[ks][tn], acc[tm][tn], 0, 0, 0);
  }

#pragma unroll
  for (int tm = 0; tm < 2; tm++)
#pragma unroll
    for (int tn = 0; tn < 4; tn++) {
      const int col = n0 + tn * 16 + l15;
      const float bias = b1[col];
#pragma unroll
      for (int r = 0; r < 4; r++) {
        const int row = m0 + tm * 16 + quad * 4 + r;
        float v = acc[tm][tn][r] + bias;
        v = v > 0.0f ? v : 0.0f;
        __bf16 bv = (__bf16)v;
        h1[(size_t)row * HIDDEN + col] = __builtin_bit_cast(unsigned short, bv);
      }
    }
}

// ---------------- GEMM2: T0 = h1 @ W2 + b2 -> fp32 (fA) AND bf16 (bA) ----------------
__global__ __launch_bounds__(256) void gemm2(
    const unsigned short* __restrict__ h1, const unsigned short* __restrict__ w2t,
    const float* __restrict__ b2, float* __restrict__ t0f,
    unsigned short* __restrict__ t0b) {
  const int wave = threadIdx.x >> 6, lane = threadIdx.x & 63;
  const int m0 = blockIdx.x * 128 + wave * 32;
  if (m0 >= M_NODES) return;
  const int l15 = lane & 15, quad = lane >> 4;

  floatx4 acc[2][4] = {};
  for (int kb = 0; kb < HIDDEN; kb += 32) {
    const int k = kb + quad * 8;
    bf16x8 afrag[2], bfrag[4];
#pragma unroll
    for (int tm = 0; tm < 2; tm++)
      afrag[tm] = *(const bf16x8*)(h1 + (size_t)(m0 + tm * 16 + l15) * HIDDEN + k);
#pragma unroll
    for (int tn = 0; tn < 4; tn++)
      bfrag[tn] = *(const bf16x8*)(w2t + (size_t)(tn * 16 + l15) * HIDDEN + k);
#pragma unroll
    for (int tm = 0; tm < 2; tm++)
#pragma unroll
      for (int tn = 0; tn < 4; tn++)
        acc[tm][tn] = __builtin_amdgcn_mfma_f32_16x16x32_bf16(afrag[tm], bfrag[tn], acc[tm][tn], 0, 0, 0);
  }

#pragma unroll
  for (int tm = 0; tm < 2; tm++)
#pragma unroll
    for (int tn = 0; tn < 4; tn++) {
      const int col = tn * 16 + l15;
      const float bias = b2[col];
#pragma unroll
      for (int r = 0; r < 4; r++) {
        const int row = m0 + tm * 16 + quad * 4 + r;
        const float v = acc[tm][tn][r] + bias;
        t0f[(size_t)row * NCLS + col] = v;
        __bf16 bv = (__bf16)v;
        t0b[(size_t)row * NCLS + col] = __builtin_bit_cast(unsigned short, bv);
      }
    }
}

// ---------------- batched dual-row gather ----------------
// Lane map: g = lane&7 selects edge-within-octet, q = lane>>3 selects col-octet.
// One global_load_dwordx4 per row-stream per 8 edges = 8 rows x 128B.
// Tails are masked iterations (clamped index, val=0). Col/val loads for
// iteration b+1 issue before iteration b's FMAs. With bucketed edge order the
// gathered rows fall in a ~2MB moving window -> L2-resident.
__device__ __forceinline__ void cheb_gather2(
    const int* __restrict__ rp, const int* __restrict__ cols,
    const float* __restrict__ vals, const __bf16* __restrict__ tb,
    int r0, int r1, int g, int q, float (&a0)[8], float (&a1)[8]) {
  const int s0 = rp[r0], e0 = rp[r0 + 1];
  const int s1 = rp[r1], e1 = rp[r1 + 1];
  const int nb0 = (e0 - s0 + 7) >> 3;
  const int nb1 = (e1 - s1 + 7) >> 3;
  const int nb = nb0 > nb1 ? nb0 : nb1;
  const char* tbb = (const char*)tb;
  const int qoff = q << 4;

  int i0 = s0 + g, i1 = s1 + g;
  int idx0 = i0 < e0 ? i0 : (e0 - 1); idx0 = idx0 > 0 ? idx0 : 0;
  int idx1 = i1 < e1 ? i1 : (e1 - 1); idx1 = idx1 > 0 ? idx1 : 0;
  int c0 = cols[idx0], c1 = cols[idx1];
  float v0 = vals[idx0]; v0 = i0 < e0 ? v0 : 0.0f;
  float v1 = vals[idx1]; v1 = i1 < e1 ? v1 : 0.0f;

  for (int b = 0; b < nb; ++b) {
    const uintx4 d0 = *(const uintx4*)(tbb + (((size_t)(unsigned)c0) << 7) + qoff);
    const uintx4 d1 = *(const uintx4*)(tbb + (((size_t)(unsigned)c1) << 7) + qoff);
    const float cv0 = v0, cv1 = v1;
    // preload next block's cols/vals (independent of the gathers above)
    i0 += 8; i1 += 8;
    idx0 = i0 < e0 ? i0 : (e0 - 1); idx0 = idx0 > 0 ? idx0 : 0;
    idx1 = i1 < e1 ? i1 : (e1 - 1); idx1 = idx1 > 0 ? idx1 : 0;
    c0 = cols[idx0]; c1 = cols[idx1];
    v0 = vals[idx0]; v0 = i0 < e0 ? v0 : 0.0f;
    v1 = vals[idx1]; v1 = i1 < e1 ? v1 : 0.0f;
#pragma unroll
    for (int j = 0; j < 4; ++j) {
      const unsigned u0 = d0[j], u1 = d1[j];
      a0[2 * j]     += cv0 * __builtin_bit_cast(float, u0 << 16);
      a0[2 * j + 1] += cv0 * __builtin_bit_cast(float, u0 & 0xffff0000u);
      a1[2 * j]     += cv1 * __builtin_bit_cast(float, u1 << 16);
      a1[2 * j + 1] += cv1 * __builtin_bit_cast(float, u1 & 0xffff0000u);
    }
  }
  // reduce over the 8 edge-classes (lane bits 0..2); all lanes end with full sums
#pragma unroll
  for (int m = 1; m <= 4; m <<= 1) {
#pragma unroll
    for (int j = 0; j < 8; ++j) {
      a0[j] += __shfl_xor(a0[j], m, 64);
      a1[j] += __shfl_xor(a1[j], m, 64);
    }
  }
}

// ---------------- SpMM first: T1 = L T0 ; z = g0*T0 + g1*T1 ----------------
__global__ __launch_bounds__(256) void spmm_first(
    const int* __restrict__ rp, const int* __restrict__ cols,
    const float* __restrict__ vals, const __bf16* __restrict__ t0b,
    const float* __restrict__ t0f, float* __restrict__ t1f,
    unsigned short* __restrict__ t1b, const float* __restrict__ gamma,
    float* __restrict__ z) {
  const int r0 = blockIdx.x * 8 + (threadIdx.x >> 6) * 2;
  const int r1 = r0 + 1;
  const int lane = threadIdx.x & 63;
  const int g = lane & 7, q = lane >> 3;
  float a0[8] = {}, a1[8] = {};
  cheb_gather2(rp, cols, vals, t0b, r0, r1, g, q, a0, a1);

  if (g == 0 || g == 4) {
    const int rr = (g == 0) ? r0 : r1;
    float s[8];
#pragma unroll
    for (int j = 0; j < 8; ++j) s[j] = (g == 0) ? a0[j] : a1[j];
    const float g0 = gamma[0], g1 = gamma[1];
    const size_t base = (size_t)rr * NCLS + q * 8;
    const floatx4 p0 = *(const floatx4*)(t0f + base);
    const floatx4 p1 = *(const floatx4*)(t0f + base + 4);
    floatx4 slo, shi, zlo, zhi;
    ushortx8 pk;
#pragma unroll
    for (int j = 0; j < 4; ++j) {
      slo[j] = s[j];
      shi[j] = s[j + 4];
      zlo[j] = g0 * p0[j] + g1 * s[j];
      zhi[j] = g0 * p1[j] + g1 * s[j + 4];
    }
#pragma unroll
    for (int j = 0; j < 8; ++j) {
      __bf16 bv = (__bf16)s[j];
      pk[j] = __builtin_bit_cast(unsigned short, bv);
    }
    *(floatx4*)(t1f + base) = slo;
    *(floatx4*)(t1f + base + 4) = shi;
    *(ushortx8*)(t1b + base) = pk;
    *(floatx4*)(z + base) = zlo;
    *(floatx4*)(z + base + 4) = zhi;
  }
}

// ---------------- SpMM step: Tn = 2 L Tc - Tp (in place over Tp); z += g[k]*Tn ----
__global__ __launch_bounds__(256) void spmm_step(
    const int* __restrict__ rp, const int* __restrict__ cols,
    const float* __restrict__ vals, const __bf16* __restrict__ tcb,
    float* __restrict__ tpf, unsigned short* __restrict__ tnb,
    const float* __restrict__ gamma, int kidx, float* __restrict__ z) {
  const int r0 = blockIdx.x * 8 + (threadIdx.x >> 6) * 2;
  const int r1 = r0 + 1;
  const int lane = threadIdx.x & 63;
  const int g = lane & 7, q = lane >> 3;
  float a0[8] = {}, a1[8] = {};
  cheb_gather2(rp, cols, vals, tcb, r0, r1, g, q, a0, a1);

  if (g == 0 || g == 4) {
    const int rr = (g == 0) ? r0 : r1;
    float s[8];
#pragma unroll
    for (int j = 0; j < 8; ++j) s[j] = (g == 0) ? a0[j] : a1[j];
    const float gk = gamma[kidx];
    const size_t base = (size_t)rr * NCLS + q * 8;
    const floatx4 p0 = *(const floatx4*)(tpf + base);
    const floatx4 p1 = *(const floatx4*)(tpf + base + 4);
    const floatx4 z0 = *(const floatx4*)(z + base);
    const floatx4 z1 = *(const floatx4*)(z + base + 4);
    floatx4 tlo, thi, zlo, zhi;
    ushortx8 pk;
#pragma unroll
    for (int j = 0; j < 4; ++j) {
      tlo[j] = 2.0f * s[j] - p0[j];
      thi[j] = 2.0f * s[j + 4] - p1[j];
      zlo[j] = z0[j] + gk * tlo[j];
      zhi[j] = z1[j] + gk * thi[j];
    }
#pragma unroll
    for (int j = 0; j < 4; ++j) {
      __bf16 blo = (__bf16)tlo[j];
      __bf16 bhi = (__bf16)thi[j];
      pk[j] = __builtin_bit_cast(unsigned short, blo);
      pk[j + 4] = __builtin_bit_cast(unsigned short, bhi);
    }
    *(floatx4*)(tpf + base) = tlo;
    *(floatx4*)(tpf + base + 4) = thi;
    *(ushortx8*)(tnb + base) = pk;
    *(floatx4*)(z + base) = zlo;
    *(floatx4*)(z + base + 4) = zhi;
  }
}

extern "C" void kernel_launch(void* const* d_in, const int* in_sizes, int n_in,
                              void* d_out, int out_size, void* d_ws, size_t ws_size,
                              hipStream_t stream) {
  const float* x     = (const float*)d_in[0];
  const int*   erow  = (const int*)d_in[1];
  const int*   ecol  = (const int*)d_in[2];
  const float* evals = (const float*)d_in[3];
  const float* W1    = (const float*)d_in[4];
  const float* b1    = (const float*)d_in[5];
  const float* W2    = (const float*)d_in[6];
  const float* b2    = (const float*)d_in[7];
  const float* gamma = (const float*)d_in[8];

  char* ws = (char*)d_ws;
  int*            rp    = (int*)(ws + WS_ROWPTR);
  unsigned short* w1t   = (unsigned short*)(ws + WS_W1T);
  unsigned short* w2t   = (unsigned short*)(ws + WS_W2T);
  unsigned short* h1    = (unsigned short*)(ws + WS_H1);
  int*            ecol2 = (int*)(ws + WS_ECOL2);
  float*          eval2 = (float*)(ws + WS_EVAL2);
  float*          fA    = (float*)(ws + WS_FA);
  float*          fB    = (float*)(ws + WS_FB);
  unsigned short* bA    = (unsigned short*)(ws + WS_BA);
  unsigned short* bB    = (unsigned short*)(ws + WS_BB);  // aliases h1 head
  float*          z     = (float*)d_out;

  prep_weights<<<576, 256, 0, stream>>>(W1, W2, w1t, w2t);
  build_rowptr<<<(M_NODES + 256) / 256, 256, 0, stream>>>(erow, rp);
  gemm1<<<M_NODES / 32, 256, 0, stream>>>(x, w1t, b1, h1);
  gemm2<<<(M_NODES + 127) / 128, 256, 0, stream>>>(h1, w2t, b2, fA, bA);
  // bucketed edges live in the dead tail of h1; must run after gemm2
  bucket_edges<<<(M_NODES + 255) / 256, 256, 0, stream>>>(rp, ecol, evals, ecol2, eval2);

  spmm_first<<<M_NODES / 8, 256, 0, stream>>>(rp, ecol2, eval2, (const __bf16*)bA,
                                              fA, fB, bB, gamma, z);

  float*          fprev = fA;
  float*          fothr = fB;
  unsigned short* bcur  = bB;
  unsigned short* bnext = bA;
  for (int k = 2; k <= 8; ++k) {
    spmm_step<<<M_NODES / 8, 256, 0, stream>>>(rp, ecol2, eval2, (const __bf16*)bcur,
                                               fprev, bnext, gamma, k, z);
    float* tf = fprev; fprev = fothr; fothr = tf;
    unsigned short* tb = bcur; bcur = bnext; bnext = tb;
  }
}

// Round 3
// 1258.233 us; speedup vs baseline: 1.1000x; 1.1000x over previous
//
#include <hip/hip_runtime.h>
#include <stdint.h>

#define M_NODES 100000
#define NUM_EDGES 3200000
#define IN_DIM 512
#define HIDDEN 256
#define NCLS 64

typedef __bf16 bf16x8 __attribute__((ext_vector_type(8)));
typedef float floatx4 __attribute__((ext_vector_type(4)));
typedef unsigned int uintx4 __attribute__((ext_vector_type(4)));
typedef unsigned short ushortx8 __attribute__((ext_vector_type(8)));

// ---- workspace layout (bytes) ----
// rp   : int[100001]            @ 0
// w1t  : ushort[256*512]        @ 400016
// w2t  : ushort[64*256]         @ 662160
// h1   : ushort[100000*256]     @ 694928     (dead after gemm2; bB aliases it)
// bB   : ushort[100000*64]      @ 694928     (alias of h1)
// fA   : float[100000*64]       @ 51894928
// fB   : float[100000*64]       @ 77494928
// bA   : ushort[100000*64]      @ 103094928
#define WS_ROWPTR 0
#define WS_W1T    400016
#define WS_W2T    662160
#define WS_H1     694928
#define WS_BB     694928
#define WS_FA     51894928
#define WS_FB     77494928
#define WS_BA     103094928

// ---------------- weight transpose + bf16 convert ----------------
__global__ __launch_bounds__(256) void prep_weights(
    const float* __restrict__ W1, const float* __restrict__ W2,
    unsigned short* __restrict__ w1t, unsigned short* __restrict__ w2t) {
  int tid = blockIdx.x * 256 + threadIdx.x;
  if (tid < IN_DIM * HIDDEN) {
    int n = tid >> 9;
    int k = tid & 511;
    __bf16 v = (__bf16)W1[k * HIDDEN + n];
    w1t[tid] = __builtin_bit_cast(unsigned short, v);
  } else {
    int idx = tid - IN_DIM * HIDDEN;
    if (idx < HIDDEN * NCLS) {
      int n = idx >> 8;
      int k = idx & 255;
      __bf16 v = (__bf16)W2[k * NCLS + n];
      w2t[idx] = __builtin_bit_cast(unsigned short, v);
    }
  }
}

// ---------------- row_ptr via binary search over sorted edge_row ----------------
__global__ __launch_bounds__(256) void build_rowptr(
    const int* __restrict__ erow, int* __restrict__ rp) {
  int r = blockIdx.x * 256 + threadIdx.x;
  if (r > M_NODES) return;
  if (r == M_NODES) { rp[r] = NUM_EDGES; return; }
  int lo = 0, hi = NUM_EDGES;
  while (lo < hi) {
    int mid = (lo + hi) >> 1;
    if (erow[mid] < r) lo = mid + 1; else hi = mid;
  }
  rp[r] = lo;
}

// ---------------- GEMM1: h1 = relu(x @ W1 + b1), bf16 out ----------------
// Previous version: load -> vmcnt(0) -> ds_write -> barrier per K-iter left the
// full HBM latency exposed with only ~2.4 resident blocks/CU (MfmaUtil 6%,
// HBM 12%, Occ 30%). v3: 3-slot register pipeline (prefetch distance 2) +
// LDS double-buffer + ONE barrier per iteration, fully unrolled so slot
// indexing is compile-time. Two 8KB tiles in flight per block.
__global__ __launch_bounds__(256) void gemm1(
    const float* __restrict__ x, const unsigned short* __restrict__ w1t,
    const float* __restrict__ b1, unsigned short* __restrict__ h1) {
  __shared__ float xs[2][32 * 68];
  const int wave = threadIdx.x >> 6, lane = threadIdx.x & 63;
  const int m0 = blockIdx.x * 32;
  const int n0 = wave * 64;
  const int l15 = lane & 15, quad = lane >> 4;
  const int t = threadIdx.x;
  const int srow = t >> 3;          // 0..31: staged row
  const int skq = (t & 7) * 8;      // float offset within row (8 floats/thread)
  const float* xbase = x + (size_t)(m0 + srow) * IN_DIM + skq;

  floatx4 st[3][2];
  // prologue: issue loads for K-tiles 0 and 1
#pragma unroll
  for (int p = 0; p < 2; ++p) {
    st[p][0] = *(const floatx4*)(xbase + p * 64);
    st[p][1] = *(const floatx4*)(xbase + p * 64 + 4);
  }

  floatx4 acc[2][4] = {};
#pragma unroll
  for (int it = 0; it < 8; ++it) {
    const int cur = it % 3;
    const int buf = it & 1;
    // stage current tile (counted vmcnt wait: tile it+1 stays in flight)
    *(floatx4*)(&xs[buf][srow * 68 + skq]) = st[cur][0];
    *(floatx4*)(&xs[buf][srow * 68 + skq + 4]) = st[cur][1];
    // issue load for tile it+2 (distance-2 prefetch)
    if (it + 2 < 8) {
      const int nxt = (it + 2) % 3;
      st[nxt][0] = *(const floatx4*)(xbase + (it + 2) * 64);
      st[nxt][1] = *(const floatx4*)(xbase + (it + 2) * 64 + 4);
    }
    __syncthreads();

    bf16x8 afrag[2][2];
    bf16x8 bfrag[2][4];
#pragma unroll
    for (int ks = 0; ks < 2; ks++) {
#pragma unroll
      for (int tm = 0; tm < 2; tm++) {
        const float* p = &xs[buf][(tm * 16 + l15) * 68 + ks * 32 + quad * 8];
        floatx4 a0 = *(const floatx4*)p;
        floatx4 a1 = *(const floatx4*)(p + 4);
        bf16x8 f;
        f[0] = (__bf16)a0[0]; f[1] = (__bf16)a0[1]; f[2] = (__bf16)a0[2]; f[3] = (__bf16)a0[3];
        f[4] = (__bf16)a1[0]; f[5] = (__bf16)a1[1]; f[6] = (__bf16)a1[2]; f[7] = (__bf16)a1[3];
        afrag[ks][tm] = f;
      }
      const int k = it * 64 + ks * 32 + quad * 8;
#pragma unroll
      for (int tn = 0; tn < 4; tn++)
        bfrag[ks][tn] = *(const bf16x8*)(w1t + (size_t)(n0 + tn * 16 + l15) * IN_DIM + k);
    }
#pragma unroll
    for (int ks = 0; ks < 2; ks++)
#pragma unroll
      for (int tm = 0; tm < 2; tm++)
#pragma unroll
        for (int tn = 0; tn < 4; tn++)
          acc[tm][tn] = __builtin_amdgcn_mfma_f32_16x16x32_bf16(afrag[ks][tm], bfrag[ks][tn], acc[tm][tn], 0, 0, 0);
    // no trailing barrier: next iteration writes the OTHER LDS buffer; its
    // barrier orders those writes against this iteration's reads.
  }

#pragma unroll
  for (int tm = 0; tm < 2; tm++)
#pragma unroll
    for (int tn = 0; tn < 4; tn++) {
      const int col = n0 + tn * 16 + l15;
      const float bias = b1[col];
#pragma unroll
      for (int r = 0; r < 4; r++) {
        const int row = m0 + tm * 16 + quad * 4 + r;
        float v = acc[tm][tn][r] + bias;
        v = v > 0.0f ? v : 0.0f;
        __bf16 bv = (__bf16)v;
        h1[(size_t)row * HIDDEN + col] = __builtin_bit_cast(unsigned short, bv);
      }
    }
}

// ---------------- GEMM2: T0 = h1 @ W2 + b2 -> fp32 (fA) AND bf16 (bA) ----------------
__global__ __launch_bounds__(256) void gemm2(
    const unsigned short* __restrict__ h1, const unsigned short* __restrict__ w2t,
    const float* __restrict__ b2, float* __restrict__ t0f,
    unsigned short* __restrict__ t0b) {
  const int wave = threadIdx.x >> 6, lane = threadIdx.x & 63;
  const int m0 = blockIdx.x * 128 + wave * 32;
  if (m0 >= M_NODES) return;
  const int l15 = lane & 15, quad = lane >> 4;

  floatx4 acc[2][4] = {};
  for (int kb = 0; kb < HIDDEN; kb += 32) {
    const int k = kb + quad * 8;
    bf16x8 afrag[2], bfrag[4];
#pragma unroll
    for (int tm = 0; tm < 2; tm++)
      afrag[tm] = *(const bf16x8*)(h1 + (size_t)(m0 + tm * 16 + l15) * HIDDEN + k);
#pragma unroll
    for (int tn = 0; tn < 4; tn++)
      bfrag[tn] = *(const bf16x8*)(w2t + (size_t)(tn * 16 + l15) * HIDDEN + k);
#pragma unroll
    for (int tm = 0; tm < 2; tm++)
#pragma unroll
      for (int tn = 0; tn < 4; tn++)
        acc[tm][tn] = __builtin_amdgcn_mfma_f32_16x16x32_bf16(afrag[tm], bfrag[tn], acc[tm][tn], 0, 0, 0);
  }

#pragma unroll
  for (int tm = 0; tm < 2; tm++)
#pragma unroll
    for (int tn = 0; tn < 4; tn++) {
      const int col = tn * 16 + l15;
      const float bias = b2[col];
#pragma unroll
      for (int r = 0; r < 4; r++) {
        const int row = m0 + tm * 16 + quad * 4 + r;
        const float v = acc[tm][tn][r] + bias;
        t0f[(size_t)row * NCLS + col] = v;
        __bf16 bv = (__bf16)v;
        t0b[(size_t)row * NCLS + col] = __builtin_bit_cast(unsigned short, bv);
      }
    }
}

// ---------------- pipelined dual-row gather ----------------
// Lane map: g = lane&7 selects edge-within-octet, q = lane>>3 selects col-octet.
// One global_load_dwordx4 per row-stream per 8 edges = 8 rows x 128B.
// NEW: 2-octet-deep software pipeline -- gathers for octet b+2 are issued while
// octet b is consumed, so each wave keeps ~4 gather instructions (4KB) in
// flight instead of stalling on same-iteration gathers. Discriminates
// latency-bound vs fabric-rate-bound. Tails are masked (clamped idx, val=0).
__device__ __forceinline__ void cheb_gather2(
    const int* __restrict__ rp, const int* __restrict__ cols,
    const float* __restrict__ vals, const __bf16* __restrict__ tb,
    int r0, int r1, int g, int q, float (&a0)[8], float (&a1)[8]) {
  const int s0 = rp[r0], e0 = rp[r0 + 1];
  const int s1 = rp[r1], e1 = rp[r1 + 1];
  const int nb0 = (e0 - s0 + 7) >> 3;
  const int nb1 = (e1 - s1 + 7) >> 3;
  const int nb = nb0 > nb1 ? nb0 : nb1;   // wave-uniform (r0,r1 uniform per wave)
  const char* tbb = (const char*)tb;
  const int qoff = q << 4;

  // cols/vals for octet b (both row streams), clamped+masked
#define LDCV(B, C0, C1, V0, V1)                                            \
  {                                                                        \
    int i0 = s0 + (B) * 8 + g, i1 = s1 + (B) * 8 + g;                      \
    int idx0 = i0 < e0 ? i0 : (e0 - 1); idx0 = idx0 > 0 ? idx0 : 0;        \
    int idx1 = i1 < e1 ? i1 : (e1 - 1); idx1 = idx1 > 0 ? idx1 : 0;        \
    C0 = cols[idx0]; C1 = cols[idx1];                                      \
    float t0_ = vals[idx0], t1_ = vals[idx1];                              \
    V0 = (i0 < e0) ? t0_ : 0.0f;                                           \
    V1 = (i1 < e1) ? t1_ : 0.0f;                                           \
  }
#define GAT(C) (*(const uintx4*)(tbb + (((size_t)(unsigned)(C)) << 7) + qoff))

  int cA0, cA1, cB0 = 0, cB1 = 0, cN0 = 0, cN1 = 0;
  float vA0, vA1, vB0 = 0.0f, vB1 = 0.0f, vN0 = 0.0f, vN1 = 0.0f;
  uintx4 dA0, dA1, dB0 = {}, dB1 = {};

  LDCV(0, cA0, cA1, vA0, vA1);
  dA0 = GAT(cA0); dA1 = GAT(cA1);
  if (nb > 1) {
    LDCV(1, cB0, cB1, vB0, vB1);
    dB0 = GAT(cB0); dB1 = GAT(cB1);
  }
  if (nb > 2) LDCV(2, cN0, cN1, vN0, vN1);

  for (int b = 0; b < nb; ++b) {
    const uintx4 d0 = dA0, d1 = dA1;
    const float cv0 = vA0, cv1 = vA1;
    // rotate: A <- B; issue new B for octet b+2; preload cols/vals for b+3
    dA0 = dB0; dA1 = dB1; vA0 = vB0; vA1 = vB1;
    if (b + 2 < nb) {
      dB0 = GAT(cN0); dB1 = GAT(cN1);
      vB0 = vN0; vB1 = vN1;
      if (b + 3 < nb) LDCV(b + 3, cN0, cN1, vN0, vN1);
    }
#pragma unroll
    for (int j = 0; j < 4; ++j) {
      const unsigned u0 = d0[j], u1 = d1[j];
      a0[2 * j]     += cv0 * __builtin_bit_cast(float, u0 << 16);
      a0[2 * j + 1] += cv0 * __builtin_bit_cast(float, u0 & 0xffff0000u);
      a1[2 * j]     += cv1 * __builtin_bit_cast(float, u1 << 16);
      a1[2 * j + 1] += cv1 * __builtin_bit_cast(float, u1 & 0xffff0000u);
    }
  }
#undef LDCV
#undef GAT

  // reduce over the 8 edge-classes (lane bits 0..2); all lanes end with full sums
#pragma unroll
  for (int m = 1; m <= 4; m <<= 1) {
#pragma unroll
    for (int j = 0; j < 8; ++j) {
      a0[j] += __shfl_xor(a0[j], m, 64);
      a1[j] += __shfl_xor(a1[j], m, 64);
    }
  }
}

// ---------------- SpMM first: T1 = L T0 ; z = g0*T0 + g1*T1 ----------------
__global__ __launch_bounds__(256) void spmm_first(
    const int* __restrict__ rp, const int* __restrict__ cols,
    const float* __restrict__ vals, const __bf16* __restrict__ t0b,
    const float* __restrict__ t0f, float* __restrict__ t1f,
    unsigned short* __restrict__ t1b, const float* __restrict__ gamma,
    float* __restrict__ z) {
  const int r0 = blockIdx.x * 8 + (threadIdx.x >> 6) * 2;
  const int r1 = r0 + 1;
  const int lane = threadIdx.x & 63;
  const int g = lane & 7, q = lane >> 3;
  float a0[8] = {}, a1[8] = {};
  cheb_gather2(rp, cols, vals, t0b, r0, r1, g, q, a0, a1);

  // epilogue: lanes g==0 handle r0, lanes g==4 handle r1 (16 active lanes)
  if (g == 0 || g == 4) {
    const int rr = (g == 0) ? r0 : r1;
    float s[8];
#pragma unroll
    for (int j = 0; j < 8; ++j) s[j] = (g == 0) ? a0[j] : a1[j];
    const float g0 = gamma[0], g1 = gamma[1];
    const size_t base = (size_t)rr * NCLS + q * 8;
    const floatx4 p0 = *(const floatx4*)(t0f + base);
    const floatx4 p1 = *(const floatx4*)(t0f + base + 4);
    floatx4 slo, shi, zlo, zhi;
    ushortx8 pk;
#pragma unroll
    for (int j = 0; j < 4; ++j) {
      slo[j] = s[j];
      shi[j] = s[j + 4];
      zlo[j] = g0 * p0[j] + g1 * s[j];
      zhi[j] = g0 * p1[j] + g1 * s[j + 4];
    }
#pragma unroll
    for (int j = 0; j < 8; ++j) {
      __bf16 bv = (__bf16)s[j];
      pk[j] = __builtin_bit_cast(unsigned short, bv);
    }
    *(floatx4*)(t1f + base) = slo;
    *(floatx4*)(t1f + base + 4) = shi;
    *(ushortx8*)(t1b + base) = pk;
    *(floatx4*)(z + base) = zlo;
    *(floatx4*)(z + base + 4) = zhi;
  }
}

// ---------------- SpMM step: Tn = 2 L Tc - Tp (in place over Tp); z += g[k]*Tn ----
__global__ __launch_bounds__(256) void spmm_step(
    const int* __restrict__ rp, const int* __restrict__ cols,
    const float* __restrict__ vals, const __bf16* __restrict__ tcb,
    float* __restrict__ tpf, unsigned short* __restrict__ tnb,
    const float* __restrict__ gamma, int kidx, float* __restrict__ z) {
  const int r0 = blockIdx.x * 8 + (threadIdx.x >> 6) * 2;
  const int r1 = r0 + 1;
  const int lane = threadIdx.x & 63;
  const int g = lane & 7, q = lane >> 3;
  float a0[8] = {}, a1[8] = {};
  cheb_gather2(rp, cols, vals, tcb, r0, r1, g, q, a0, a1);

  if (g == 0 || g == 4) {
    const int rr = (g == 0) ? r0 : r1;
    float s[8];
#pragma unroll
    for (int j = 0; j < 8; ++j) s[j] = (g == 0) ? a0[j] : a1[j];
    const float gk = gamma[kidx];
    const size_t base = (size_t)rr * NCLS + q * 8;
    const floatx4 p0 = *(const floatx4*)(tpf + base);
    const floatx4 p1 = *(const floatx4*)(tpf + base + 4);
    const floatx4 z0 = *(const floatx4*)(z + base);
    const floatx4 z1 = *(const floatx4*)(z + base + 4);
    floatx4 tlo, thi, zlo, zhi;
    ushortx8 pk;
#pragma unroll
    for (int j = 0; j < 4; ++j) {
      tlo[j] = 2.0f * s[j] - p0[j];
      thi[j] = 2.0f * s[j + 4] - p1[j];
      zlo[j] = z0[j] + gk * tlo[j];
      zhi[j] = z1[j] + gk * thi[j];
    }
#pragma unroll
    for (int j = 0; j < 4; ++j) {
      __bf16 blo = (__bf16)tlo[j];
      __bf16 bhi = (__bf16)thi[j];
      pk[j] = __builtin_bit_cast(unsigned short, blo);
      pk[j + 4] = __builtin_bit_cast(unsigned short, bhi);
    }
    *(floatx4*)(tpf + base) = tlo;
    *(floatx4*)(tpf + base + 4) = thi;
    *(ushortx8*)(tnb + base) = pk;
    *(floatx4*)(z + base) = zlo;
    *(floatx4*)(z + base + 4) = zhi;
  }
}

extern "C" void kernel_launch(void* const* d_in, const int* in_sizes, int n_in,
                              void* d_out, int out_size, void* d_ws, size_t ws_size,
                              hipStream_t stream) {
  const float* x     = (const float*)d_in[0];
  const int*   erow  = (const int*)d_in[1];
  const int*   ecol  = (const int*)d_in[2];
  const float* evals = (const float*)d_in[3];
  const float* W1    = (const float*)d_in[4];
  const float* b1    = (const float*)d_in[5];
  const float* W2    = (const float*)d_in[6];
  const float* b2    = (const float*)d_in[7];
  const float* gamma = (const float*)d_in[8];

  char* ws = (char*)d_ws;
  int*            rp  = (int*)(ws + WS_ROWPTR);
  unsigned short* w1t = (unsigned short*)(ws + WS_W1T);
  unsigned short* w2t = (unsigned short*)(ws + WS_W2T);
  unsigned short* h1  = (unsigned short*)(ws + WS_H1);
  float*          fA  = (float*)(ws + WS_FA);
  float*          fB  = (float*)(ws + WS_FB);
  unsigned short* bA  = (unsigned short*)(ws + WS_BA);
  unsigned short* bB  = (unsigned short*)(ws + WS_BB);  // aliases h1 (dead after gemm2)
  float*          z   = (float*)d_out;

  prep_weights<<<576, 256, 0, stream>>>(W1, W2, w1t, w2t);
  build_rowptr<<<(M_NODES + 256) / 256, 256, 0, stream>>>(erow, rp);
  gemm1<<<M_NODES / 32, 256, 0, stream>>>(x, w1t, b1, h1);
  gemm2<<<(M_NODES + 127) / 128, 256, 0, stream>>>(h1, w2t, b2, fA, bA);

  spmm_first<<<M_NODES / 8, 256, 0, stream>>>(rp, ecol, evals, (const __bf16*)bA,
                                              fA, fB, bB, gamma, z);

  float*          fprev = fA;
  float*          fothr = fB;
  unsigned short* bcur  = bB;
  unsigned short* bnext = bA;
  for (int k = 2; k <= 8; ++k) {
    spmm_step<<<M_NODES / 8, 256, 0, stream>>>(rp, ecol, evals, (const __bf16*)bcur,
                                               fprev, bnext, gamma, k, z);
    float* tf = fprev; fprev = fothr; fothr = tf;
    unsigned short* tb = bcur; bcur = bnext; bnext = tb;
  }
}